// Round 6
// baseline (386.313 us; speedup 1.0000x reference)
//
#include <hip/hip_runtime.h>
#include <math.h>

#define NB 16
#define CIN 128
#define COUT 128
#define SDIM 512
#define HH 128
#define WW 128

typedef __bf16 bf16x8 __attribute__((ext_vector_type(8)));
typedef float f32x4 __attribute__((ext_vector_type(4)));

static constexpr size_t WA_OFF = 8192;                          // after s (2048 f32)
static constexpr size_t WA_ELEMS = (size_t)NB * 9 * COUT * CIN; // 2,359,296 bf16
static constexpr size_t XT_OFF = WA_OFF + WA_ELEMS * 2;
static constexpr size_t XT_ELEMS = (size_t)NB * 130 * 130 * CIN;
static constexpr size_t WS_NEEDED = XT_OFF + XT_ELEMS * 2;

__device__ __forceinline__ unsigned short f32_bf16(float f) {
  unsigned int x = __float_as_uint(f);
  x += 0x7fffu + ((x >> 16) & 1u);
  return (unsigned short)(x >> 16);
}

__device__ __forceinline__ void gl_lds16(const void* g, void* l) {
  __builtin_amdgcn_global_load_lds((const __attribute__((address_space(1))) void*)g,
                                   (__attribute__((address_space(3))) void*)l, 16, 0, 0);
}

// ---------------- K0: s[b][cin] = style[b] . mod_w[cin] ----------------
__global__ void k_style(const float* __restrict__ style, const float* __restrict__ mod_w,
                        float* __restrict__ s) {
  int b = blockIdx.x, ci = threadIdx.x;
  const float4* st = (const float4*)(style + (size_t)b * SDIM);
  const float4* mw = (const float4*)(mod_w + (size_t)ci * SDIM);
  float acc = 0.f;
  for (int i = 0; i < SDIM / 4; ++i) {
    float4 a = st[i], m = mw[i];
    acc += a.x * m.x + a.y * m.y + a.z * m.z + a.w * m.w;
  }
  s[b * CIN + ci] = acc;
}

// ---------------- K1: demod + wA[b][tap][cout][cin] (bf16) ----------------
__global__ void k_wprep(const float* __restrict__ weight, const float* __restrict__ s,
                        unsigned short* __restrict__ wA) {
  int co = blockIdx.x, b = blockIdx.y, ci = threadIdx.x;
  const float scale = 0.029462782549439483f; // 1/sqrt(128*9)
  float sv = s[b * CIN + ci];
  const float* wp = weight + ((size_t)co * CIN + ci) * 9;
  float u[9], ss = 0.f;
#pragma unroll
  for (int t = 0; t < 9; ++t) { u[t] = scale * wp[t] * sv; ss += u[t] * u[t]; }
#pragma unroll
  for (int off = 32; off; off >>= 1) ss += __shfl_down(ss, off, 64);
  __shared__ float red[2];
  if ((threadIdx.x & 63) == 0) red[threadIdx.x >> 6] = ss;
  __syncthreads();
  float demod = rsqrtf(red[0] + red[1] + 1e-8f);
#pragma unroll
  for (int t = 0; t < 9; ++t)
    wA[((size_t)(b * 9 + t) * COUT + co) * CIN + ci] = f32_bf16(u[t] * demod);
}

// ---------------- K2: xt[b][hb][wb][cin] transpose, halo written in-kernel ----
__global__ void k_xt(const float* __restrict__ x, unsigned short* __restrict__ xt) {
  int hb = blockIdx.x, b = blockIdx.y;
  int t = threadIdx.x;
  unsigned short* orow = xt + ((size_t)b * 130 + hb) * 130 * CIN;
  if (hb == 0 || hb == 129) {
    uint4 z = {0u, 0u, 0u, 0u};
    for (int u = t; u < 2080; u += 256) ((uint4*)orow)[u] = z;
    return;
  }
  __shared__ unsigned short lds[128][132]; // [w][c]
  int h = hb - 1;
  const float* xrow = x + (size_t)b * CIN * HH * WW + (size_t)h * WW;
  for (int i = 0; i < 32; ++i) {
    int flat = i * 256 + t;
    int w = flat & 127, cp = flat >> 7;
    float a0 = xrow[(size_t)(2 * cp) * HH * WW + w];
    float a1 = xrow[(size_t)(2 * cp + 1) * HH * WW + w];
    unsigned int pk = (unsigned int)f32_bf16(a0) | ((unsigned int)f32_bf16(a1) << 16);
    *(unsigned int*)&lds[w][2 * cp] = pk;
  }
  __syncthreads();
  if (t < 32) {
    int side = t >> 4, g = t & 15;
    uint4 z = {0u, 0u, 0u, 0u};
    ((uint4*)(orow + (side ? (size_t)129 * CIN : 0)))[g] = z;
  }
  for (int i = 0; i < 8; ++i) {
    int u = i * 256 + t;
    int w = u >> 4, cg = u & 15;
    uint2 v0 = *(const uint2*)&lds[w][cg * 8];
    uint2 v1 = *(const uint2*)&lds[w][cg * 8 + 4];
    uint4 v = {v0.x, v0.y, v1.x, v1.y};
    *(uint4*)(orow + (size_t)(1 + w) * CIN + cg * 8) = v;
  }
}

// ---------------- K3: conv via 9 shifted MFMA-GEMMs ----------------
// EXACT round-2 structure (grid (64,NB) b-major, cell-major staging goff,
// linear [cell][g] LDS, 16x16 tile, 64B store runs) with ONE change:
// 8 waves x acc[4][4] (wave = M64 x N64) -> VGPR 64, 4 waves/SIMD.
__launch_bounds__(512, 4)
__global__ void k_conv(const unsigned short* __restrict__ xt,
                       const unsigned short* __restrict__ wA,
                       const float* __restrict__ noise,
                       const float* __restrict__ nw,
                       float* __restrict__ out) {
  __shared__ uint4 ldsraw[2][1536]; // 18*18 cells * 4 units = 1296 used
  int b = blockIdx.y;
  int tile = blockIdx.x;
  int th = (tile >> 3) * 16, tw = (tile & 7) * 16;

  int t = threadIdx.x;
  int lane = t & 63, wv = t >> 6;
  int wm = wv >> 2, wn = wv & 3;
  int lc = lane & 15, lg = lane >> 4;

  f32x4 acc[4][4];
#pragma unroll
  for (int mi = 0; mi < 4; ++mi)
#pragma unroll
    for (int j = 0; j < 4; ++j) acc[mi][j] = (f32x4){0.f, 0.f, 0.f, 0.f};

  const unsigned short* xtile = xt + ((size_t)b * 130 + th) * 130 * CIN + (size_t)tw * CIN;
  const unsigned short* wbase = wA + (size_t)b * 9 * COUT * CIN
                                + (size_t)(wm * 64 + lc) * CIN + lg * 8;

  // cell-major staging offsets (r2 pattern: 4 consecutive lanes = 64B contiguous)
  int goff[3];
#pragma unroll
  for (int i = 0; i < 3; ++i) {
    int u = i * 512 + t;
    int cell = u >> 2, g = u & 3;
    int y = cell / 18, xx = cell - y * 18;
    goff[i] = (y * 130 + xx) * CIN + g * 8;
  }
  int ldsslot = wv * 64;

  auto STAGE = [&](int bb, int q) {
    const unsigned short* xq = xtile + q * 32;
#pragma unroll
    for (int i = 0; i < 3; ++i) {
      int u = i * 512 + t;
      if (u < 1296)
        gl_lds16(xq + goff[i], &ldsraw[bb][i * 512 + ldsslot]);
    }
  };

  STAGE(0, 0);
  __syncthreads();

  for (int q = 0; q < 4; ++q) {
    if (q < 3) STAGE((q + 1) & 1, q + 1); // issue next-chunk loads BEFORE compute
    const unsigned short* bb_lds = (const unsigned short*)&ldsraw[q & 1][0];
    const unsigned short* wq = wbase + (size_t)q * 32;
#pragma unroll
    for (int ky = 0; ky < 3; ++ky) {
#pragma unroll
      for (int kx = 0; kx < 3; ++kx) {
        int tap = ky * 3 + kx;
        bf16x8 af[4];
#pragma unroll
        for (int mi = 0; mi < 4; ++mi)
          af[mi] = *(const bf16x8*)(wq + ((size_t)tap * COUT + mi * 16) * CIN);
#pragma unroll
        for (int j = 0; j < 4; ++j) {
          int row = wn * 4 + j + ky;
          int unit = (row * 18 + lc + kx) * 4 + lg;
          bf16x8 bv = *((const bf16x8*)bb_lds + unit);
#pragma unroll
          for (int mi = 0; mi < 4; ++mi)
            acc[mi][j] = __builtin_amdgcn_mfma_f32_16x16x32_bf16(af[mi], bv, acc[mi][j], 0, 0, 0);
        }
      }
    }
    __syncthreads();
  }

  // ---- epilogue: + noise_weight[cout]*noise, store fp32 (64B runs, r2 pattern) ----
  float nwv[4][4];
#pragma unroll
  for (int mi = 0; mi < 4; ++mi)
#pragma unroll
    for (int rr = 0; rr < 4; ++rr) nwv[mi][rr] = nw[wm * 64 + mi * 16 + lg * 4 + rr];
#pragma unroll
  for (int j = 0; j < 4; ++j) {
    int hh = th + wn * 4 + j, ww = tw + lc;
    float nv = noise[((size_t)b * HH + hh) * WW + ww];
#pragma unroll
    for (int mi = 0; mi < 4; ++mi) {
      int cobase = wm * 64 + mi * 16 + lg * 4;
#pragma unroll
      for (int rr = 0; rr < 4; ++rr)
        out[(((size_t)b * COUT + cobase + rr) * HH + hh) * WW + ww] = acc[mi][j][rr] + nwv[mi][rr] * nv;
    }
  }
}

extern "C" void kernel_launch(void* const* d_in, const int* in_sizes, int n_in,
                              void* d_out, int out_size, void* d_ws, size_t ws_size,
                              hipStream_t stream) {
  const float* x      = (const float*)d_in[0];
  const float* style  = (const float*)d_in[1];
  const float* noise  = (const float*)d_in[2];
  const float* weight = (const float*)d_in[3];
  const float* mod_w  = (const float*)d_in[4];
  const float* nw     = (const float*)d_in[5];
  float* out = (float*)d_out;
  char* ws = (char*)d_ws;
  if (ws_size < WS_NEEDED) return;

  float* s = (float*)ws;
  unsigned short* wA = (unsigned short*)(ws + WA_OFF);
  unsigned short* xt = (unsigned short*)(ws + XT_OFF);

  k_style<<<dim3(NB), dim3(CIN), 0, stream>>>(style, mod_w, s);
  k_wprep<<<dim3(COUT, NB), dim3(CIN), 0, stream>>>(weight, s, wA);
  k_xt<<<dim3(130, NB), dim3(256), 0, stream>>>(x, xt);
  k_conv<<<dim3(64, NB), dim3(512), 0, stream>>>(xt, wA, noise, nw, out);
}

// Round 7
// 351.871 us; speedup vs baseline: 1.0979x; 1.0979x over previous
//
#include <hip/hip_runtime.h>
#include <math.h>

#define NB 16
#define CIN 128
#define COUT 128
#define SDIM 512
#define HH 128
#define WW 128

typedef __bf16 bf16x8 __attribute__((ext_vector_type(8)));
typedef float f32x4 __attribute__((ext_vector_type(4)));

static constexpr size_t WA_OFF = 8192;                          // after s (2048 f32)
static constexpr size_t WA_ELEMS = (size_t)NB * 9 * COUT * CIN; // 2,359,296 bf16
static constexpr size_t XT_OFF = WA_OFF + WA_ELEMS * 2;
static constexpr size_t XT_ELEMS = (size_t)NB * 130 * 130 * CIN;
static constexpr size_t WS_NEEDED = XT_OFF + XT_ELEMS * 2;

__device__ __forceinline__ unsigned short f32_bf16(float f) {
  unsigned int x = __float_as_uint(f);
  x += 0x7fffu + ((x >> 16) & 1u);
  return (unsigned short)(x >> 16);
}

__device__ __forceinline__ void gl_lds16(const void* g, void* l) {
  __builtin_amdgcn_global_load_lds((const __attribute__((address_space(1))) void*)g,
                                   (__attribute__((address_space(3))) void*)l, 16, 0, 0);
}

// ---------------- K0: s[b][cin] = style[b] . mod_w[cin] ----------------
__global__ void k_style(const float* __restrict__ style, const float* __restrict__ mod_w,
                        float* __restrict__ s) {
  int b = blockIdx.x, ci = threadIdx.x;
  const float4* st = (const float4*)(style + (size_t)b * SDIM);
  const float4* mw = (const float4*)(mod_w + (size_t)ci * SDIM);
  float acc = 0.f;
  for (int i = 0; i < SDIM / 4; ++i) {
    float4 a = st[i], m = mw[i];
    acc += a.x * m.x + a.y * m.y + a.z * m.z + a.w * m.w;
  }
  s[b * CIN + ci] = acc;
}

// ---------------- K1: demod + wA[b][tap][cout][cin] (bf16) ----------------
__global__ void k_wprep(const float* __restrict__ weight, const float* __restrict__ s,
                        unsigned short* __restrict__ wA) {
  int co = blockIdx.x, b = blockIdx.y, ci = threadIdx.x;
  const float scale = 0.029462782549439483f; // 1/sqrt(128*9)
  float sv = s[b * CIN + ci];
  const float* wp = weight + ((size_t)co * CIN + ci) * 9;
  float u[9], ss = 0.f;
#pragma unroll
  for (int t = 0; t < 9; ++t) { u[t] = scale * wp[t] * sv; ss += u[t] * u[t]; }
#pragma unroll
  for (int off = 32; off; off >>= 1) ss += __shfl_down(ss, off, 64);
  __shared__ float red[2];
  if ((threadIdx.x & 63) == 0) red[threadIdx.x >> 6] = ss;
  __syncthreads();
  float demod = rsqrtf(red[0] + red[1] + 1e-8f);
#pragma unroll
  for (int t = 0; t < 9; ++t)
    wA[((size_t)(b * 9 + t) * COUT + co) * CIN + ci] = f32_bf16(u[t] * demod);
}

// ---------------- K2: xt[b][hb][wb][cin] transpose, halo written in-kernel ----
__global__ void k_xt(const float* __restrict__ x, unsigned short* __restrict__ xt) {
  int hb = blockIdx.x, b = blockIdx.y;
  int t = threadIdx.x;
  unsigned short* orow = xt + ((size_t)b * 130 + hb) * 130 * CIN;
  if (hb == 0 || hb == 129) {
    uint4 z = {0u, 0u, 0u, 0u};
    for (int u = t; u < 2080; u += 256) ((uint4*)orow)[u] = z;
    return;
  }
  __shared__ unsigned short lds[128][132]; // [w][c]
  int h = hb - 1;
  const float* xrow = x + (size_t)b * CIN * HH * WW + (size_t)h * WW;
  for (int i = 0; i < 32; ++i) {
    int flat = i * 256 + t;
    int w = flat & 127, cp = flat >> 7;
    float a0 = xrow[(size_t)(2 * cp) * HH * WW + w];
    float a1 = xrow[(size_t)(2 * cp + 1) * HH * WW + w];
    unsigned int pk = (unsigned int)f32_bf16(a0) | ((unsigned int)f32_bf16(a1) << 16);
    *(unsigned int*)&lds[w][2 * cp] = pk;
  }
  __syncthreads();
  if (t < 32) {
    int side = t >> 4, g = t & 15;
    uint4 z = {0u, 0u, 0u, 0u};
    ((uint4*)(orow + (side ? (size_t)129 * CIN : 0)))[g] = z;
  }
  for (int i = 0; i < 8; ++i) {
    int u = i * 256 + t;
    int w = u >> 4, cg = u & 15;
    uint2 v0 = *(const uint2*)&lds[w][cg * 8];
    uint2 v1 = *(const uint2*)&lds[w][cg * 8 + 4];
    uint4 v = {v0.x, v0.y, v1.x, v1.y};
    *(uint4*)(orow + (size_t)(1 + w) * CIN + cg * 8) = v;
  }
}

// ---------------- K3: conv via 9 shifted MFMA-GEMMs ----------------
// Block tile = 128 cout x (8 hh x 32 ww): every 128B out line is owned by ONE
// block, and its two 64B halves are stored by ADJACENT instructions of the
// same wave -> L2 merges to full-line writebacks (no cross-block RMW).
// 512 thr = 8 waves: wm = co half, wn = hh pair; wave = M64 x (2hh x 32ww),
// acc[4][4] -> VGPR ~64, 3 blocks/CU (LDS 45KB).
__launch_bounds__(512, 4)
__global__ void k_conv(const unsigned short* __restrict__ xt,
                       const unsigned short* __restrict__ wA,
                       const float* __restrict__ noise,
                       const float* __restrict__ nw,
                       float* __restrict__ out) {
  __shared__ uint4 ldsraw[2][1408]; // 10*34 cells * 4 units = 1360 used
  int b = blockIdx.y;
  int tile = blockIdx.x;                 // 16 hbands x 4 wbands
  int th = (tile >> 2) * 8, tw = (tile & 3) * 32;

  int t = threadIdx.x;
  int lane = t & 63, wv = t >> 6;
  int wm = wv >> 2, wn = wv & 3;
  int lc = lane & 15, lg = lane >> 4;

  f32x4 acc[4][4]; // [mi][jr*2+jc]
#pragma unroll
  for (int mi = 0; mi < 4; ++mi)
#pragma unroll
    for (int j = 0; j < 4; ++j) acc[mi][j] = (f32x4){0.f, 0.f, 0.f, 0.f};

  const unsigned short* xtile = xt + ((size_t)b * 130 + th) * 130 * CIN + (size_t)tw * CIN;
  const unsigned short* wbase = wA + (size_t)b * 9 * COUT * CIN
                                + (size_t)(wm * 64 + lc) * CIN + lg * 8;

  // cell-major staging offsets (4 consecutive lanes = 64B contiguous source)
  int goff[3];
#pragma unroll
  for (int i = 0; i < 3; ++i) {
    int u = i * 512 + t;
    int cell = u >> 2, g = u & 3;
    int y = cell / 34, xx = cell - y * 34;
    goff[i] = (y * 130 + xx) * CIN + g * 8;
  }
  int ldsslot = wv * 64;

  auto STAGE = [&](int bb, int q) {
    const unsigned short* xq = xtile + q * 32;
#pragma unroll
    for (int i = 0; i < 3; ++i) {
      int u = i * 512 + t;
      if (u < 1360)
        gl_lds16(xq + goff[i], &ldsraw[bb][i * 512 + ldsslot]);
    }
  };

  STAGE(0, 0);
  __syncthreads();

  for (int q = 0; q < 4; ++q) {
    if (q < 3) STAGE((q + 1) & 1, q + 1); // issue next-chunk loads BEFORE compute
    const unsigned short* bb_lds = (const unsigned short*)&ldsraw[q & 1][0];
    const unsigned short* wq = wbase + (size_t)q * 32;
#pragma unroll
    for (int ky = 0; ky < 3; ++ky) {
#pragma unroll
      for (int kx = 0; kx < 3; ++kx) {
        int tap = ky * 3 + kx;
        bf16x8 af[4];
#pragma unroll
        for (int mi = 0; mi < 4; ++mi)
          af[mi] = *(const bf16x8*)(wq + ((size_t)tap * COUT + mi * 16) * CIN);
#pragma unroll
        for (int j = 0; j < 4; ++j) {
          int jr = j >> 1, jc = j & 1;
          int row = wn * 2 + jr + ky;          // 0..9
          int col = jc * 16 + lc + kx;         // 0..33
          int unit = (row * 34 + col) * 4 + lg;
          bf16x8 bv = *((const bf16x8*)bb_lds + unit);
#pragma unroll
          for (int mi = 0; mi < 4; ++mi)
            acc[mi][j] = __builtin_amdgcn_mfma_f32_16x16x32_bf16(af[mi], bv, acc[mi][j], 0, 0, 0);
        }
      }
    }
    __syncthreads();
  }

  // ---- epilogue: adjacent jc=0/jc=1 stores complete each 128B line in-wave ----
  float nwv[4][4];
#pragma unroll
  for (int mi = 0; mi < 4; ++mi)
#pragma unroll
    for (int rr = 0; rr < 4; ++rr) nwv[mi][rr] = nw[wm * 64 + mi * 16 + lg * 4 + rr];
#pragma unroll
  for (int jr = 0; jr < 2; ++jr) {
    int hh = th + wn * 2 + jr;
    const float* nrow = noise + ((size_t)b * HH + hh) * WW + tw;
    float nv0 = nrow[lc], nv1 = nrow[16 + lc];
#pragma unroll
    for (int mi = 0; mi < 4; ++mi) {
      int cobase = wm * 64 + mi * 16 + lg * 4;
#pragma unroll
      for (int rr = 0; rr < 4; ++rr) {
        float* orow = out + (((size_t)b * COUT + cobase + rr) * HH + hh) * WW + tw;
        orow[lc]      = acc[mi][jr * 2 + 0][rr] + nwv[mi][rr] * nv0;
        orow[16 + lc] = acc[mi][jr * 2 + 1][rr] + nwv[mi][rr] * nv1;
      }
    }
  }
}

extern "C" void kernel_launch(void* const* d_in, const int* in_sizes, int n_in,
                              void* d_out, int out_size, void* d_ws, size_t ws_size,
                              hipStream_t stream) {
  const float* x      = (const float*)d_in[0];
  const float* style  = (const float*)d_in[1];
  const float* noise  = (const float*)d_in[2];
  const float* weight = (const float*)d_in[3];
  const float* mod_w  = (const float*)d_in[4];
  const float* nw     = (const float*)d_in[5];
  float* out = (float*)d_out;
  char* ws = (char*)d_ws;
  if (ws_size < WS_NEEDED) return;

  float* s = (float*)ws;
  unsigned short* wA = (unsigned short*)(ws + WA_OFF);
  unsigned short* xt = (unsigned short*)(ws + XT_OFF);

  k_style<<<dim3(NB), dim3(CIN), 0, stream>>>(style, mod_w, s);
  k_wprep<<<dim3(COUT, NB), dim3(CIN), 0, stream>>>(weight, s, wA);
  k_xt<<<dim3(130, NB), dim3(256), 0, stream>>>(x, xt);
  k_conv<<<dim3(64, NB), dim3(512), 0, stream>>>(xt, wA, noise, nw, out);
}

// Round 8
// 281.240 us; speedup vs baseline: 1.3736x; 1.2511x over previous
//
#include <hip/hip_runtime.h>
#include <math.h>

#define NB 16
#define CIN 128
#define COUT 128
#define SDIM 512
#define HH 128
#define WW 128

typedef __bf16 bf16x8 __attribute__((ext_vector_type(8)));
typedef float f32x4 __attribute__((ext_vector_type(4)));

static constexpr size_t WA_OFF = 8192;                          // after s (2048 f32)
static constexpr size_t WA_ELEMS = (size_t)NB * 9 * COUT * CIN; // 2,359,296 bf16
static constexpr size_t XT_OFF = WA_OFF + WA_ELEMS * 2;
static constexpr size_t XT_ELEMS = (size_t)NB * 130 * 130 * CIN;
static constexpr size_t WS_NEEDED = XT_OFF + XT_ELEMS * 2;

__device__ __forceinline__ unsigned short f32_bf16(float f) {
  unsigned int x = __float_as_uint(f);
  x += 0x7fffu + ((x >> 16) & 1u);
  return (unsigned short)(x >> 16);
}

__device__ __forceinline__ void gl_lds16(const void* g, void* l) {
  __builtin_amdgcn_global_load_lds((const __attribute__((address_space(1))) void*)g,
                                   (__attribute__((address_space(3))) void*)l, 16, 0, 0);
}

// ---------------- K0: s[b][cin] = style[b] . mod_w[cin] ----------------
__global__ void k_style(const float* __restrict__ style, const float* __restrict__ mod_w,
                        float* __restrict__ s) {
  int b = blockIdx.x, ci = threadIdx.x;
  const float4* st = (const float4*)(style + (size_t)b * SDIM);
  const float4* mw = (const float4*)(mod_w + (size_t)ci * SDIM);
  float acc = 0.f;
  for (int i = 0; i < SDIM / 4; ++i) {
    float4 a = st[i], m = mw[i];
    acc += a.x * m.x + a.y * m.y + a.z * m.z + a.w * m.w;
  }
  s[b * CIN + ci] = acc;
}

// ---------------- K1: demod + wA[b][tap][cout][cin] (bf16) ----------------
__global__ void k_wprep(const float* __restrict__ weight, const float* __restrict__ s,
                        unsigned short* __restrict__ wA) {
  int co = blockIdx.x, b = blockIdx.y, ci = threadIdx.x;
  const float scale = 0.029462782549439483f; // 1/sqrt(128*9)
  float sv = s[b * CIN + ci];
  const float* wp = weight + ((size_t)co * CIN + ci) * 9;
  float u[9], ss = 0.f;
#pragma unroll
  for (int t = 0; t < 9; ++t) { u[t] = scale * wp[t] * sv; ss += u[t] * u[t]; }
#pragma unroll
  for (int off = 32; off; off >>= 1) ss += __shfl_down(ss, off, 64);
  __shared__ float red[2];
  if ((threadIdx.x & 63) == 0) red[threadIdx.x >> 6] = ss;
  __syncthreads();
  float demod = rsqrtf(red[0] + red[1] + 1e-8f);
#pragma unroll
  for (int t = 0; t < 9; ++t)
    wA[((size_t)(b * 9 + t) * COUT + co) * CIN + ci] = f32_bf16(u[t] * demod);
}

// ---------------- K2: xt[b][hb][wb][cin] transpose, halo written in-kernel ----
__global__ void k_xt(const float* __restrict__ x, unsigned short* __restrict__ xt) {
  int hb = blockIdx.x, b = blockIdx.y;
  int t = threadIdx.x;
  unsigned short* orow = xt + ((size_t)b * 130 + hb) * 130 * CIN;
  if (hb == 0 || hb == 129) {
    uint4 z = {0u, 0u, 0u, 0u};
    for (int u = t; u < 2080; u += 256) ((uint4*)orow)[u] = z;
    return;
  }
  __shared__ unsigned short lds[128][132]; // [w][c]
  int h = hb - 1;
  const float* xrow = x + (size_t)b * CIN * HH * WW + (size_t)h * WW;
  for (int i = 0; i < 32; ++i) {
    int flat = i * 256 + t;
    int w = flat & 127, cp = flat >> 7;
    float a0 = xrow[(size_t)(2 * cp) * HH * WW + w];
    float a1 = xrow[(size_t)(2 * cp + 1) * HH * WW + w];
    unsigned int pk = (unsigned int)f32_bf16(a0) | ((unsigned int)f32_bf16(a1) << 16);
    *(unsigned int*)&lds[w][2 * cp] = pk;
  }
  __syncthreads();
  if (t < 32) {
    int side = t >> 4, g = t & 15;
    uint4 z = {0u, 0u, 0u, 0u};
    ((uint4*)(orow + (side ? (size_t)129 * CIN : 0)))[g] = z;
  }
  for (int i = 0; i < 8; ++i) {
    int u = i * 256 + t;
    int w = u >> 4, cg = u & 15;
    uint2 v0 = *(const uint2*)&lds[w][cg * 8];
    uint2 v1 = *(const uint2*)&lds[w][cg * 8 + 4];
    uint4 v = {v0.x, v0.y, v1.x, v1.y};
    *(uint4*)(orow + (size_t)(1 + w) * CIN + cg * 8) = v;
  }
}

// ---------------- K3: conv via 9 shifted MFMA-GEMMs, A in registers ----------------
// r2 regime on purpose: 4 waves x 256 thr, 2 blocks/CU = 8 waves/CU (the
// measured-exact-writes regime). Block tile = 128 cout x (8 h x 16 w) px,
// 2048 blocks b-major. Wave = M64 x (4 rows x 16 px), acc[4][4].
// Key change vs r2: per cin-chunk, ALL 36 A-fragments (af[9 taps][4 mi]) are
// batch-loaded to registers up front; inner loop reads only B from LDS
// (1 ds_read_b128 per 4 MFMA) -> A-load latency paid once per chunk.
__launch_bounds__(256, 2)
__global__ void k_conv(const unsigned short* __restrict__ xt,
                       const unsigned short* __restrict__ wA,
                       const float* __restrict__ noise,
                       const float* __restrict__ nw,
                       float* __restrict__ out) {
  __shared__ uint4 ldsraw[2][736]; // 10 rows x 18 cols x 4 units = 720 used
  int b = blockIdx.y;
  int tile = blockIdx.x;              // 16 hbands x 8 wbands
  int th = (tile >> 3) * 8, tw = (tile & 7) * 16;

  int t = threadIdx.x;
  int lane = t & 63, wv = t >> 6;
  int wm = wv >> 1, wn = wv & 1;
  int lc = lane & 15, lg = lane >> 4;

  f32x4 acc[4][4];
#pragma unroll
  for (int mi = 0; mi < 4; ++mi)
#pragma unroll
    for (int j = 0; j < 4; ++j) acc[mi][j] = (f32x4){0.f, 0.f, 0.f, 0.f};

  const unsigned short* xtile = xt + ((size_t)b * 130 + th) * 130 * CIN + (size_t)tw * CIN;
  const unsigned short* wbase = wA + (size_t)b * 9 * COUT * CIN
                                + (size_t)(wm * 64 + lc) * CIN + lg * 8;

  // cell-major staging offsets (r2 pattern: 4 consecutive lanes = 64B contiguous)
  int goff[3];
#pragma unroll
  for (int i = 0; i < 3; ++i) {
    int u = i * 256 + t;
    int cell = u >> 2, g = u & 3;
    int y = cell / 18, xx = cell - y * 18;
    goff[i] = (y * 130 + xx) * CIN + g * 8;
  }
  int ldsslot = wv * 64;

  auto STAGE = [&](int bb, int q) {
    const unsigned short* xq = xtile + q * 32;
#pragma unroll
    for (int i = 0; i < 3; ++i) {
      int u = i * 256 + t;
      if (u < 720)
        gl_lds16(xq + goff[i], &ldsraw[bb][i * 256 + ldsslot]);
    }
  };

  STAGE(0, 0);
  __syncthreads();

  for (int q = 0; q < 4; ++q) {
    // batch-load this chunk's 36 A-fragments into registers (issued back-to-back)
    bf16x8 af[9][4];
    const unsigned short* wq = wbase + (size_t)q * 32;
#pragma unroll
    for (int tap = 0; tap < 9; ++tap)
#pragma unroll
      for (int mi = 0; mi < 4; ++mi)
        af[tap][mi] = *(const bf16x8*)(wq + ((size_t)tap * COUT + mi * 16) * CIN);

    if (q < 3) STAGE((q + 1) & 1, q + 1); // prefetch next x-chunk into other buffer

    const unsigned short* bb_lds = (const unsigned short*)&ldsraw[q & 1][0];
#pragma unroll
    for (int ky = 0; ky < 3; ++ky) {
#pragma unroll
      for (int kx = 0; kx < 3; ++kx) {
        int tap = ky * 3 + kx;
#pragma unroll
        for (int j = 0; j < 4; ++j) {
          int unit = ((wn * 4 + j + ky) * 18 + lc + kx) * 4 + lg;
          bf16x8 bv = *((const bf16x8*)bb_lds + unit);
#pragma unroll
          for (int mi = 0; mi < 4; ++mi)
            acc[mi][j] = __builtin_amdgcn_mfma_f32_16x16x32_bf16(af[tap][mi], bv, acc[mi][j], 0, 0, 0);
        }
      }
    }
    __syncthreads();
  }

  // ---- epilogue: + noise_weight[cout]*noise, store fp32 (64B runs, r2 pattern) ----
  float nwv[4][4];
#pragma unroll
  for (int mi = 0; mi < 4; ++mi)
#pragma unroll
    for (int rr = 0; rr < 4; ++rr) nwv[mi][rr] = nw[wm * 64 + mi * 16 + lg * 4 + rr];
#pragma unroll
  for (int j = 0; j < 4; ++j) {
    int hh = th + wn * 4 + j, ww = tw + lc;
    float nv = noise[((size_t)b * HH + hh) * WW + ww];
#pragma unroll
    for (int mi = 0; mi < 4; ++mi) {
      int cobase = wm * 64 + mi * 16 + lg * 4;
#pragma unroll
      for (int rr = 0; rr < 4; ++rr)
        out[(((size_t)b * COUT + cobase + rr) * HH + hh) * WW + ww] = acc[mi][j][rr] + nwv[mi][rr] * nv;
    }
  }
}

extern "C" void kernel_launch(void* const* d_in, const int* in_sizes, int n_in,
                              void* d_out, int out_size, void* d_ws, size_t ws_size,
                              hipStream_t stream) {
  const float* x      = (const float*)d_in[0];
  const float* style  = (const float*)d_in[1];
  const float* noise  = (const float*)d_in[2];
  const float* weight = (const float*)d_in[3];
  const float* mod_w  = (const float*)d_in[4];
  const float* nw     = (const float*)d_in[5];
  float* out = (float*)d_out;
  char* ws = (char*)d_ws;
  if (ws_size < WS_NEEDED) return;

  float* s = (float*)ws;
  unsigned short* wA = (unsigned short*)(ws + WA_OFF);
  unsigned short* xt = (unsigned short*)(ws + XT_OFF);

  k_style<<<dim3(NB), dim3(CIN), 0, stream>>>(style, mod_w, s);
  k_wprep<<<dim3(COUT, NB), dim3(CIN), 0, stream>>>(weight, s, wA);
  k_xt<<<dim3(130, NB), dim3(256), 0, stream>>>(x, xt);
  k_conv<<<dim3(128, NB), dim3(256), 0, stream>>>(xt, wA, noise, nw, out);
}

// Round 9
// 160.016 us; speedup vs baseline: 2.4142x; 1.7576x over previous
//
#include <hip/hip_runtime.h>
#include <math.h>

#define NB 16
#define CIN 128
#define COUT 128
#define SDIM 512
#define HH 128
#define WW 128

typedef __bf16 bf16x8 __attribute__((ext_vector_type(8)));
typedef float f32x4 __attribute__((ext_vector_type(4)));

static constexpr size_t WA_OFF = 8192;                          // after s (2048 f32)
static constexpr size_t WA_ELEMS = (size_t)NB * 9 * COUT * CIN; // 2,359,296 bf16
static constexpr size_t XT_OFF = WA_OFF + WA_ELEMS * 2;
static constexpr size_t XT_ELEMS = (size_t)NB * 130 * 130 * CIN;
static constexpr size_t WS_NEEDED = XT_OFF + XT_ELEMS * 2;

__device__ __forceinline__ unsigned short f32_bf16(float f) {
  unsigned int x = __float_as_uint(f);
  x += 0x7fffu + ((x >> 16) & 1u);
  return (unsigned short)(x >> 16);
}

__device__ __forceinline__ void gl_lds16(const void* g, void* l) {
  __builtin_amdgcn_global_load_lds((const __attribute__((address_space(1))) void*)g,
                                   (__attribute__((address_space(3))) void*)l, 16, 0, 0);
}

// ---------------- K0: s[b][cin] = style[b] . mod_w[cin] ----------------
__global__ void k_style(const float* __restrict__ style, const float* __restrict__ mod_w,
                        float* __restrict__ s) {
  int b = blockIdx.x, ci = threadIdx.x;
  const float4* st = (const float4*)(style + (size_t)b * SDIM);
  const float4* mw = (const float4*)(mod_w + (size_t)ci * SDIM);
  float acc = 0.f;
  for (int i = 0; i < SDIM / 4; ++i) {
    float4 a = st[i], m = mw[i];
    acc += a.x * m.x + a.y * m.y + a.z * m.z + a.w * m.w;
  }
  s[b * CIN + ci] = acc;
}

// ---------------- K1: demod + wA[b][tap][cout][cin] (bf16) ----------------
__global__ void k_wprep(const float* __restrict__ weight, const float* __restrict__ s,
                        unsigned short* __restrict__ wA) {
  int co = blockIdx.x, b = blockIdx.y, ci = threadIdx.x;
  const float scale = 0.029462782549439483f; // 1/sqrt(128*9)
  float sv = s[b * CIN + ci];
  const float* wp = weight + ((size_t)co * CIN + ci) * 9;
  float u[9], ss = 0.f;
#pragma unroll
  for (int t = 0; t < 9; ++t) { u[t] = scale * wp[t] * sv; ss += u[t] * u[t]; }
#pragma unroll
  for (int off = 32; off; off >>= 1) ss += __shfl_down(ss, off, 64);
  __shared__ float red[2];
  if ((threadIdx.x & 63) == 0) red[threadIdx.x >> 6] = ss;
  __syncthreads();
  float demod = rsqrtf(red[0] + red[1] + 1e-8f);
#pragma unroll
  for (int t = 0; t < 9; ++t)
    wA[((size_t)(b * 9 + t) * COUT + co) * CIN + ci] = f32_bf16(u[t] * demod);
}

// ---------------- K2: xt[b][hb][wb][cin] transpose, halo written in-kernel ----
__global__ void k_xt(const float* __restrict__ x, unsigned short* __restrict__ xt) {
  int hb = blockIdx.x, b = blockIdx.y;
  int t = threadIdx.x;
  unsigned short* orow = xt + ((size_t)b * 130 + hb) * 130 * CIN;
  if (hb == 0 || hb == 129) {
    uint4 z = {0u, 0u, 0u, 0u};
    for (int u = t; u < 2080; u += 256) ((uint4*)orow)[u] = z;
    return;
  }
  __shared__ unsigned short lds[128][132]; // [w][c]
  int h = hb - 1;
  const float* xrow = x + (size_t)b * CIN * HH * WW + (size_t)h * WW;
  for (int i = 0; i < 32; ++i) {
    int flat = i * 256 + t;
    int w = flat & 127, cp = flat >> 7;
    float a0 = xrow[(size_t)(2 * cp) * HH * WW + w];
    float a1 = xrow[(size_t)(2 * cp + 1) * HH * WW + w];
    unsigned int pk = (unsigned int)f32_bf16(a0) | ((unsigned int)f32_bf16(a1) << 16);
    *(unsigned int*)&lds[w][2 * cp] = pk;
  }
  __syncthreads();
  if (t < 32) {
    int side = t >> 4, g = t & 15;
    uint4 z = {0u, 0u, 0u, 0u};
    ((uint4*)(orow + (side ? (size_t)129 * CIN : 0)))[g] = z;
  }
  for (int i = 0; i < 8; ++i) {
    int u = i * 256 + t;
    int w = u >> 4, cg = u & 15;
    uint2 v0 = *(const uint2*)&lds[w][cg * 8];
    uint2 v1 = *(const uint2*)&lds[w][cg * 8 + 4];
    uint4 v = {v0.x, v0.y, v1.x, v1.y};
    *(uint4*)(orow + (size_t)(1 + w) * CIN + cg * 8) = v;
  }
}

// ---------------- K3: conv via 9 shifted MFMA-GEMMs ----------------
// EXACT r2 shell (grid (64,NB), 4 waves x 256 thr, acc[4][8], 16x16 tile,
// cell-major dbuf global_load_lds staging, 64B-run stores). ONE change:
// one-tap-ahead A-fragment register double-buffer (afA/afB): each tap body
// issues tap+1's 4 global loads first, then its 8x(ds_read+4 MFMA) consume
// the PREVIOUS batch -> compiler emits counted vmcnt, A-latency hides under
// the prior tap's compute. +16 VGPR, concurrency unchanged (2 waves/SIMD).
__launch_bounds__(256)
__global__ void k_conv(const unsigned short* __restrict__ xt,
                       const unsigned short* __restrict__ wA,
                       const float* __restrict__ noise,
                       const float* __restrict__ nw,
                       float* __restrict__ out) {
  __shared__ uint4 ldsraw[2][1536]; // 18x18 cells x 4 units = 1296 used
  int b = blockIdx.y;
  int tile = blockIdx.x;
  int th = (tile >> 3) * 16, tw = (tile & 7) * 16;
  int t = threadIdx.x;
  int lane = t & 63, wv = t >> 6;
  int wm = wv >> 1, wn = wv & 1;
  int lc = lane & 15, lg = lane >> 4;

  f32x4 acc[4][8];
#pragma unroll
  for (int mi = 0; mi < 4; ++mi)
#pragma unroll
    for (int j = 0; j < 8; ++j) acc[mi][j] = (f32x4){0.f, 0.f, 0.f, 0.f};

  const unsigned short* xtile = xt + ((size_t)b * 130 + th) * 130 * CIN + (size_t)tw * CIN;
  const unsigned short* wbase = wA + (size_t)b * 9 * COUT * CIN
                                + (size_t)(wm * 64 + lc) * CIN + lg * 8;

  // r2 cell-major staging offsets (4 consecutive lanes = 64B contiguous)
  int goff[6];
#pragma unroll
  for (int i = 0; i < 6; ++i) {
    int idx = i * 256 + t;
    int cell = idx >> 2, g = idx & 3;
    int y = cell / 18, xx = cell - y * 18;
    goff[i] = (y * 130 + xx) * CIN + g * 8;
  }
  int ldsslot = wv * 64;

  auto STAGE = [&](int bb, int q) {
    const unsigned short* xq = xtile + q * 32;
#pragma unroll
    for (int i = 0; i < 6; ++i) {
      int idx = i * 256 + t;
      if (idx < 1296)
        gl_lds16(xq + goff[i], &ldsraw[bb][i * 256 + ldsslot]);
    }
  };

  // tap body: prefetch tap+1 A-frags into nxt, compute with cur
  auto TAPBODY = [&](int tap, bf16x8 (&cur)[4], bf16x8 (&nxt)[4],
                     const unsigned short* wq, const unsigned short* bb_lds) {
    if (tap < 8) {
#pragma unroll
      for (int mi = 0; mi < 4; ++mi)
        nxt[mi] = *(const bf16x8*)(wq + ((size_t)(tap + 1) * COUT + mi * 16) * CIN);
    }
    int ky = tap / 3, kx = tap - 3 * (tap / 3);
#pragma unroll
    for (int j = 0; j < 8; ++j) {
      int unit = ((wn * 8 + j + ky) * 18 + (lc + kx)) * 4 + lg;
      bf16x8 bv = *((const bf16x8*)bb_lds + unit);
#pragma unroll
      for (int mi = 0; mi < 4; ++mi)
        acc[mi][j] = __builtin_amdgcn_mfma_f32_16x16x32_bf16(cur[mi], bv, acc[mi][j], 0, 0, 0);
    }
  };

  STAGE(0, 0);
  __syncthreads();

  for (int q = 0; q < 4; ++q) {
    if (q < 3) STAGE((q + 1) & 1, q + 1); // issue next-chunk x loads BEFORE compute
    const unsigned short* bb_lds = (const unsigned short*)&ldsraw[q & 1][0];
    const unsigned short* wq = wbase + (size_t)q * 32;

    bf16x8 afA[4], afB[4];
#pragma unroll
    for (int mi = 0; mi < 4; ++mi) // tap 0
      afA[mi] = *(const bf16x8*)(wq + (size_t)mi * 16 * CIN);

    TAPBODY(0, afA, afB, wq, bb_lds);
    TAPBODY(1, afB, afA, wq, bb_lds);
    TAPBODY(2, afA, afB, wq, bb_lds);
    TAPBODY(3, afB, afA, wq, bb_lds);
    TAPBODY(4, afA, afB, wq, bb_lds);
    TAPBODY(5, afB, afA, wq, bb_lds);
    TAPBODY(6, afA, afB, wq, bb_lds);
    TAPBODY(7, afB, afA, wq, bb_lds);
    TAPBODY(8, afA, afB, wq, bb_lds);

    __syncthreads();
  }

  // ---- epilogue: + noise_weight[cout]*noise, store fp32 (64B runs, r2 pattern) ----
  float nwv[4][4];
#pragma unroll
  for (int mi = 0; mi < 4; ++mi)
#pragma unroll
    for (int rr = 0; rr < 4; ++rr) nwv[mi][rr] = nw[wm * 64 + mi * 16 + lg * 4 + rr];
#pragma unroll
  for (int j = 0; j < 8; ++j) {
    int hh = th + wn * 8 + j, ww = tw + lc;
    float nv = noise[((size_t)b * HH + hh) * WW + ww];
#pragma unroll
    for (int mi = 0; mi < 4; ++mi) {
      int cobase = wm * 64 + mi * 16 + lg * 4;
#pragma unroll
      for (int rr = 0; rr < 4; ++rr)
        out[(((size_t)b * COUT + cobase + rr) * HH + hh) * WW + ww] = acc[mi][j][rr] + nwv[mi][rr] * nv;
    }
  }
}

extern "C" void kernel_launch(void* const* d_in, const int* in_sizes, int n_in,
                              void* d_out, int out_size, void* d_ws, size_t ws_size,
                              hipStream_t stream) {
  const float* x      = (const float*)d_in[0];
  const float* style  = (const float*)d_in[1];
  const float* noise  = (const float*)d_in[2];
  const float* weight = (const float*)d_in[3];
  const float* mod_w  = (const float*)d_in[4];
  const float* nw     = (const float*)d_in[5];
  float* out = (float*)d_out;
  char* ws = (char*)d_ws;
  if (ws_size < WS_NEEDED) return;

  float* s = (float*)ws;
  unsigned short* wA = (unsigned short*)(ws + WA_OFF);
  unsigned short* xt = (unsigned short*)(ws + XT_OFF);

  k_style<<<dim3(NB), dim3(CIN), 0, stream>>>(style, mod_w, s);
  k_wprep<<<dim3(COUT, NB), dim3(CIN), 0, stream>>>(weight, s, wA);
  k_xt<<<dim3(130, NB), dim3(256), 0, stream>>>(x, xt);
  k_conv<<<dim3(64, NB), dim3(256), 0, stream>>>(xt, wA, noise, nw, out);
}